// Round 4
// baseline (5001.999 us; speedup 1.0000x reference)
//
#include <hip/hip_runtime.h>
#include <cstdint>
#include <cstddef>

#define T_ 512
#define B_ 64
#define I_ 512
#define H_ 512

typedef __attribute__((ext_vector_type(8))) short short8;
typedef __attribute__((ext_vector_type(4))) float f32x4;

#define MFMA(a, b, c) __builtin_amdgcn_mfma_f32_16x16x32_bf16((a), (b), (c), 0, 0, 0)

__device__ __forceinline__ unsigned short f2bf(float f) {
  union { float f; unsigned u; } v; v.f = f;
  unsigned r = v.u + 0x7fffu + ((v.u >> 16) & 1u);
  return (unsigned short)(r >> 16);
}

__device__ __forceinline__ float sigm(float x) { return 1.0f / (1.0f + __expf(-x)); }
__device__ __forceinline__ float tanh_fast(float x) {
  float e = __expf(2.0f * x);
  return 1.0f - 2.0f / (e + 1.0f);
}

__device__ __forceinline__ short8 loadWfrag(const float* __restrict__ p) {
  float4 a = ((const float4*)p)[0];
  float4 b = ((const float4*)p)[1];
  short8 r;
  r[0] = (short)f2bf(a.x); r[1] = (short)f2bf(a.y);
  r[2] = (short)f2bf(a.z); r[3] = (short)f2bf(a.w);
  r[4] = (short)f2bf(b.x); r[5] = (short)f2bf(b.y);
  r[6] = (short)f2bf(b.z); r[7] = (short)f2bf(b.w);
  return r;
}

// ---- cache-scope-controlled raw ops.
// fast path " sc0": bypass L1, served by XCD-local L2 (valid ONLY if the
// runtime probe proves co-XCD placement + sc0 coherence semantics).
// fallback " sc0 sc1": bypass L1+L2, served by LLC (proven by prior rounds).
template <bool LLC>
__device__ __forceinline__ void stw(void* p, unsigned v) {
  if constexpr (LLC)
    asm volatile("global_store_dword %0, %1, off sc0 sc1" :: "v"(p), "v"(v) : "memory");
  else
    asm volatile("global_store_dword %0, %1, off sc0" :: "v"(p), "v"(v) : "memory");
}
template <bool LLC>
__device__ __forceinline__ int ldf(const void* p) {
  int v;
  if constexpr (LLC)
    asm volatile("global_load_dword %0, %1, off sc0 sc1\n\ts_waitcnt vmcnt(0)"
                 : "=v"(v) : "v"(p) : "memory");
  else
    asm volatile("global_load_dword %0, %1, off sc0\n\ts_waitcnt vmcnt(0)"
                 : "=v"(v) : "v"(p) : "memory");
  return v;
}

#define LDH1(i, OFF, SC)                                                      \
  asm volatile("global_load_dwordx4 %0, %1, off offset:" OFF SC               \
               : "=v"(hf[i]) : "v"(hsrc) : "memory")
#define LDH_ALL(SC)                                                           \
  LDH1(0, "0", SC); LDH1(1, "64", SC); LDH1(2, "128", SC); LDH1(3, "192", SC);\
  LDH1(4, "256", SC); LDH1(5, "320", SC); LDH1(6, "384", SC);                 \
  LDH1(7, "448", SC); LDH1(8, "512", SC); LDH1(9, "576", SC);                 \
  LDH1(10, "640", SC); LDH1(11, "704", SC); LDH1(12, "768", SC);              \
  LDH1(13, "832", SC); LDH1(14, "896", SC); LDH1(15, "960", SC)

#define LDX1(i, OFF)                                                          \
  asm volatile("global_load_dwordx4 %0, %1, off offset:" OFF                  \
               : "=v"(xf[i]) : "v"(xsrc) : "memory")
#define LDX_ALL()                                                             \
  LDX1(0, "0"); LDX1(1, "64"); LDX1(2, "128"); LDX1(3, "192");                \
  LDX1(4, "256"); LDX1(5, "320"); LDX1(6, "384"); LDX1(7, "448");             \
  LDX1(8, "512"); LDX1(9, "576"); LDX1(10, "640"); LDX1(11, "704");           \
  LDX1(12, "768"); LDX1(13, "832"); LDX1(14, "896"); LDX1(15, "960")

// ---- prep: convert X (T,B,I) fp32 -> bf16 in ws. 16384x256 threads.
__global__ void prep_x(const float4* __restrict__ x, ushort4* __restrict__ xb) {
  int i = blockIdx.x * 256 + threadIdx.x;
  float4 v = x[i];
  ushort4 o;
  o.x = f2bf(v.x); o.y = f2bf(v.y); o.z = f2bf(v.z); o.w = f2bf(v.w);
  xb[i] = o;
}

// ---- prep: h0 -> per-cluster parity-0 buffers; init control regions.
// flags int layout: [0,8192) wave flags =0; [8192,10240) xcds =-1;
// [10240,10368) probe data =-1; [10368,10624) probe handshake =0;
// [10624,10752) verdicts =-1.
__global__ void prep_init(const float* __restrict__ h0f, const float* __restrict__ h0b,
                          unsigned short* __restrict__ hbufs, int* __restrict__ flags) {
  int i = blockIdx.x * 256 + threadIdx.x;
  int d = i >> 15;
  int b = (i >> 9) & 63;
  int u = i & 511;
  int q = b >> 4;
  int c = d * 4 + q;                 // cluster
  int lb = b & 15;                   // local batch row
  const float* src = d ? h0b : h0f;
  hbufs[(size_t)c * 16384 + lb * 512 + u] = f2bf(src[b * 512 + u]);
  if (i < 8192) flags[i] = 0;
  else if (i < 10368) flags[i] = -1;         // xcds + probe data
  else if (i < 10624) flags[i] = 0;          // probe handshake
  else if (i < 10752) flags[i] = -1;         // verdicts
}

// ---- main loop, cache-scope templated (identical logic both scopes) ----
template <bool LLC>
__device__ __forceinline__ void run_loop(
    int dir, int q, int lane, int lm, int quad, int lb0, int hb,
    const short8 (&wx)[2][16], const short8 (&wh)[2][16],
    const float (&bsum)[4], float (&creg)[4], float (&hlast)[4],
    short8 (&xf)[16],
    const char* xb_lane, const char* hload_base, char* hstore_base,
    int* myflag, const int* pollp, float* __restrict__ out) {
  const int ab0 = 16 * q + lb0;           // absolute batch of reg r=0
  const int hb2 = hb + (lm & ~1);         // out/h-store unit column

  for (int s = 0; s < 512; ++s) {
    const int t = dir ? (511 - s) : s;

    // wait xf prefetch (and drain prev-iter stores), then x MFMAs (no h dep)
    asm volatile("s_waitcnt vmcnt(0)" ::: "memory");
    __builtin_amdgcn_sched_barrier(0);
    f32x4 acc0 = {0.f, 0.f, 0.f, 0.f};
    f32x4 acc1 = {0.f, 0.f, 0.f, 0.f};
#pragma unroll
    for (int kk = 0; kk < 16; ++kk) {
      acc0 = MFMA(xf[kk], wx[0][kk], acc0);
      acc1 = MFMA(xf[kk], wx[1][kk], acc1);
    }

    // poll: lane L waits for cluster producer wave L to finish step s-1;
    // wave proceeds only when all 64 lanes pass (divergence join).
    {
      int fv = ldf<LLC>(pollp);
      while (fv < s) { __builtin_amdgcn_s_sleep(1); fv = ldf<LLC>(pollp); }
    }

    // h A-fragment loads: row = local batch lm, cols quad*8 + kk*32 units
    const char* hsrc = hload_base + (size_t)(s & 1) * 16384;
    short8 hf[16];
    if constexpr (LLC) { LDH_ALL(" sc0 sc1"); } else { LDH_ALL(" sc0"); }
    asm volatile("s_waitcnt vmcnt(0)" ::: "memory");
    __builtin_amdgcn_sched_barrier(0);

#pragma unroll
    for (int kk = 0; kk < 16; ++kk) {
      acc0 = MFMA(hf[kk], wh[0][kk], acc0);
      acc1 = MFMA(hf[kk], wh[1][kk], acc1);
    }

    // gate exchange within lane pair (lm ^ 8); D: col=lane&15, row=quad*4+reg
    float hv[4];
#pragma unroll
    for (int r = 0; r < 4; ++r) {
      float p0 = __shfl_xor(acc0[r], 8, 64);
      float p1 = __shfl_xor(acc1[r], 8, 64);
      float gi  = (lm < 8 ? acc0[r] : p0) + bsum[0];
      float gfr = (lm < 8 ? p0 : acc0[r]) + bsum[1];
      float gg  = (lm < 8 ? acc1[r] : p1) + bsum[2];
      float go  = (lm < 8 ? p1 : acc1[r]) + bsum[3];
      float cn = sigm(gfr) * creg[r] + sigm(gi) * tanh_fast(gg);
      creg[r] = cn;
      hv[r] = sigm(go) * tanh_fast(cn);
      hlast[r] = hv[r];
    }
    float q0 = __shfl_xor(hv[0], 1, 64), q1 = __shfl_xor(hv[1], 1, 64);
    float q2 = __shfl_xor(hv[2], 1, 64), q3 = __shfl_xor(hv[3], 1, 64);

    // h stores: lane lm<8 writes 2x4B; even lanes rows lb0+0/1, odd rows lb0+2/3
    {
      char* hdst = hstore_base + (size_t)((s + 1) & 1) * 16384;
      const int sel = lm & 1;
      unsigned wA = sel ? ((unsigned)f2bf(q2) | ((unsigned)f2bf(hv[2]) << 16))
                        : ((unsigned)f2bf(hv[0]) | ((unsigned)f2bf(q0) << 16));
      unsigned wB = sel ? ((unsigned)f2bf(q3) | ((unsigned)f2bf(hv[3]) << 16))
                        : ((unsigned)f2bf(hv[1]) | ((unsigned)f2bf(q1) << 16));
      char* pA = hdst + (size_t)(lb0 + 2 * sel) * 1024;
      if (lm < 8) { stw<LLC>(pA, wA); stw<LLC>(pA + 1024, wB); }
    }

    // x prefetch for next step (16 asm loads; stay in flight across the post)
    {
      int sn = s + 1 < 512 ? s + 1 : 511;
      int tn = dir ? (511 - sn) : sn;
      const char* xsrc = xb_lane + (size_t)tn * 65536;
      LDX_ALL();
    }
    // drain the 2 h-store instrs only (16 youngest = prefetch outstanding)
    asm volatile("s_waitcnt vmcnt(16)" ::: "memory");
    if (lane == 0) stw<LLC>(myflag, (unsigned)(s + 1));

    // out stores (plain cached; off the critical path, after the post)
    if (lm < 8) {
      const int sel = lm & 1;
      float2 vA = sel ? make_float2(q2, hv[2]) : make_float2(hv[0], q0);
      float2 vB = sel ? make_float2(q3, hv[3]) : make_float2(hv[1], q1);
      float* ob = out + (size_t)t * 65536 + dir * 512 + hb2;
      *(float2*)(ob + (size_t)(ab0 + 2 * sel) * 1024) = vA;
      *(float2*)(ob + (size_t)(ab0 + 2 * sel + 1) * 1024) = vB;
    }
  }
}

// ---- persistent bidirectional LSTM. grid=128 (8 clusters x 16 members), block=256.
// Cluster c = bid&7 = (dir, batch-quarter): 16 batches, full H=512; member
// m = bid>>3 owns units [32m,32m+32). All h/flag traffic cluster-internal.
// Scope selection is runtime-VERIFIED, always-terminating:
//  (1) all blocks publish s_getreg id via LLC; accept only if each cluster's
//      16 members agree AND the 8 cluster values are pairwise distinct
//      (rejects garbage-constant or non-XCD-correlated registers);
//  (2) per-cluster sc0 coherence probe with bounded timeout (member1 sc0-
//      stores magic, member0 polls sc0 after priming its L1) -> verdict via
//      LLC. Any failure -> LLC-scope loop (proven semantics, R2 speed).
__global__ __launch_bounds__(256, 1) void lstm_coop(
    const unsigned short* __restrict__ xbf,
    unsigned short* __restrict__ hbufs,
    int* __restrict__ flags,
    const float* __restrict__ Wih_f, const float* __restrict__ Whh_f,
    const float* __restrict__ bih_f, const float* __restrict__ bhh_f,
    const float* __restrict__ c0_f,
    const float* __restrict__ Wih_b, const float* __restrict__ Whh_b,
    const float* __restrict__ bih_b, const float* __restrict__ bhh_b,
    const float* __restrict__ c0_b,
    float* __restrict__ out) {
  const int tid = threadIdx.x;
  const int wave = tid >> 6;
  const int lane = tid & 63;
  const int quad = lane >> 4;
  const int lm = lane & 15;

  const int wg = blockIdx.x;
  const int cluster = wg & 7;
  const int member = wg >> 3;
  const int dir = cluster >> 2;
  const int q = cluster & 3;
  const int hb = member * 32 + wave * 8;   // first of this wave's 8 units
  const int lb0 = quad * 4;                // local batch of reg r=0

  int* xcds = flags + 8192;

  // ---- publish my hw id FIRST (visible early via LLC) ----
  {
    unsigned xcc = __builtin_amdgcn_s_getreg(6164) & 0xFu;  // hwreg(20,0,4) = XCC_ID?
    if (tid == 0) stw<true>(xcds + (size_t)wg * 16, xcc);
  }

  const float* Wih = dir ? Wih_b : Wih_f;
  const float* Whh = dir ? Whh_b : Whh_f;
  const float* bih = dir ? bih_b : bih_f;
  const float* bhh = dir ? bhh_b : bhh_f;
  const float* c0  = dir ? c0_b  : c0_f;

  // ---- weight fragments: 32 gate rows x K=512, both matrices, in registers ----
  short8 wx[2][16], wh[2][16];
#pragma unroll
  for (int nt = 0; nt < 2; ++nt) {
    int nl = nt * 16 + lm;
    int row = (nl >> 3) * 512 + hb + (nl & 7);
#pragma unroll
    for (int kk = 0; kk < 16; ++kk) {
      int k = kk * 32 + quad * 8;
      wx[nt][kk] = loadWfrag(Wih + (size_t)row * 512 + k);
      wh[nt][kk] = loadWfrag(Whh + (size_t)row * 512 + k);
    }
  }

  const int u = lm & 7;
  float bsum[4];
#pragma unroll
  for (int g = 0; g < 4; ++g)
    bsum[g] = bih[g * 512 + hb + u] + bhh[g * 512 + hb + u];

  float creg[4], hlast[4];
#pragma unroll
  for (int r = 0; r < 4; ++r) {
    creg[r] = c0[(size_t)(16 * q + lb0 + r) * 512 + hb + u];
    hlast[r] = 0.f;
  }

  // ---- pointers ----
  char* hclus = (char*)hbufs + (size_t)cluster * 32768;           // 2 x 16KB parity
  const char* hload_base = hclus + (size_t)lm * 1024 + quad * 16;
  char* hstore_base = hclus + (size_t)(hb + (lm & ~1)) * 2;
  int* myflag = flags + ((size_t)cluster * 64 + member * 4 + wave) * 16;
  const int* pollp = flags + ((size_t)cluster * 64 + lane) * 16;
  const char* xb_lane = (const char*)xbf + (size_t)(16 * q + lm) * 1024 + quad * 16;

  // ---- gather all 128 published ids; plausibility check (grid-uniform) ----
  bool lcl;
  {
    const int* p0 = xcds + (size_t)lane * 16;
    const int* p1 = xcds + (size_t)(lane + 64) * 16;
    int e0 = ldf<true>(p0), e1 = ldf<true>(p1);
    while (e0 == -1 || e1 == -1) {
      __builtin_amdgcn_s_sleep(8);
      e0 = ldf<true>(p0); e1 = ldf<true>(p1);
    }
    // lane l holds entries for wgs l and l+64, both of cluster l&7;
    // lane c (c<8) holds cluster c's member-0 value in e0.
    int ref = __shfl(e0, lane & 7, 64);
    bool all_uni = __all(e0 == ref && e1 == ref);
    bool dup = false;
#pragma unroll
    for (int j = 0; j < 8; ++j) {
      int vj = __shfl(e0, j, 64);
      if (lane < 8 && j < lane && vj == e0) dup = true;
    }
    bool distinct8 = __all(!(lane < 8 && dup));
    lcl = all_uni && distinct8;
  }

  // ---- per-cluster sc0 coherence probe (bounded; verdict via LLC) ----
  int* probep = flags + 10240 + cluster * 16;
  int* hs     = flags + 10368 + cluster * 32;   // +0 primed, +16 stored
  int* verd   = flags + 10624 + cluster * 16;
  if (lcl) {
    if (member == 0 && tid == 0) {
      (void)ldf<false>(probep);                       // prime (-1; may cache L1)
      stw<true>(hs, 1u);                              // primed
      while (ldf<true>(hs + 16) == 0) __builtin_amdgcn_s_sleep(8);
      int ok = 0;
      for (int it = 0; it < 20000; ++it) {
        if (ldf<false>(probep) == 0x5A5A5A5A) { ok = 1; break; }
        __builtin_amdgcn_s_sleep(2);
      }
      stw<true>(verd, (unsigned)ok);
    } else if (member == 1 && tid == 0) {
      while (ldf<true>(hs) == 0) __builtin_amdgcn_s_sleep(8);
      stw<false>(probep, 0x5A5A5A5Au);                // the sc0 store under test
      asm volatile("s_waitcnt vmcnt(0)" ::: "memory");
      stw<true>(hs + 16, 1u);                         // stored
    }
  }
  bool fast = false;
  if (lcl) {
    int vd = ldf<true>(verd);
    while (vd == -1) { __builtin_amdgcn_s_sleep(8); vd = ldf<true>(verd); }
    fast = (vd == 1);
  }

  // ---- initial x prefetch ----
  short8 xf[16];
  {
    const char* xsrc = xb_lane + (size_t)(dir ? 511 : 0) * 65536;
    LDX_ALL();
  }

  if (fast)
    run_loop<false>(dir, q, lane, lm, quad, lb0, hb, wx, wh, bsum, creg, hlast,
                    xf, xb_lane, hload_base, hstore_base, myflag, pollp, out);
  else
    run_loop<true>(dir, q, lane, lm, quad, lb0, hb, wx, wh, bsum, creg, hlast,
                   xf, xb_lane, hload_base, hstore_base, myflag, pollp, out);

  // ---- final hT, cT ----
  if (lm < 8) {
    float* obase = out + 33554432 + dir * 65536;
#pragma unroll
    for (int r = 0; r < 4; ++r) {
      obase[(size_t)(16 * q + lb0 + r) * 512 + hb + u] = hlast[r];
      obase[32768 + (size_t)(16 * q + lb0 + r) * 512 + hb + u] = creg[r];
    }
  }
}

extern "C" void kernel_launch(void* const* d_in, const int* in_sizes, int n_in,
                              void* d_out, int out_size, void* d_ws, size_t ws_size,
                              hipStream_t stream) {
  (void)in_sizes; (void)n_in; (void)out_size; (void)ws_size;

  const float* X     = (const float*)d_in[0];
  const float* h0_f  = (const float*)d_in[1];
  const float* c0_f  = (const float*)d_in[2];
  const float* h0_b  = (const float*)d_in[3];
  const float* c0_b  = (const float*)d_in[4];
  const float* Wih_f = (const float*)d_in[5];
  const float* Whh_f = (const float*)d_in[6];
  const float* bih_f = (const float*)d_in[7];
  const float* bhh_f = (const float*)d_in[8];
  const float* Wih_b = (const float*)d_in[9];
  const float* Whh_b = (const float*)d_in[10];
  const float* bih_b = (const float*)d_in[11];
  const float* bhh_b = (const float*)d_in[12];
  float* out = (float*)d_out;

  unsigned short* xbf   = (unsigned short*)d_ws;                      // 33,554,432 B
  unsigned short* hbufs = (unsigned short*)((char*)d_ws + 33554432);  //    262,144 B (8 clusters x 2 x 16KB)
  int* flags            = (int*)((char*)d_ws + 33554432 + 262144);    //     43,008 B control block

  prep_x<<<16384, 256, 0, stream>>>((const float4*)X, (ushort4*)xbf);
  prep_init<<<256, 256, 0, stream>>>(h0_f, h0_b, hbufs, flags);

  lstm_coop<<<dim3(128), dim3(256), 0, stream>>>(
      xbf, hbufs, flags,
      Wih_f, Whh_f, bih_f, bhh_f, c0_f,
      Wih_b, Whh_b, bih_b, bhh_b, c0_b,
      out);
}

// Round 5
// 3620.361 us; speedup vs baseline: 1.3816x; 1.3816x over previous
//
#include <hip/hip_runtime.h>
#include <cstdint>
#include <cstddef>

#define T_ 512
#define B_ 64
#define I_ 512
#define H_ 512
#define SENT32 0x7FC07FC0

typedef __attribute__((ext_vector_type(8))) short short8;
typedef __attribute__((ext_vector_type(4))) float f32x4;
typedef __attribute__((ext_vector_type(4))) int i32x4;

#define MFMA(a, b, c) __builtin_amdgcn_mfma_f32_16x16x32_bf16((a), (b), (c), 0, 0, 0)

__device__ __forceinline__ unsigned short f2bf(float f) {
  union { float f; unsigned u; } v; v.f = f;
  unsigned r = v.u + 0x7fffu + ((v.u >> 16) & 1u);
  return (unsigned short)(r >> 16);
}

__device__ __forceinline__ float sigm(float x) { return 1.0f / (1.0f + __expf(-x)); }
__device__ __forceinline__ float tanh_fast(float x) {
  float e = __expf(2.0f * x);
  return 1.0f - 2.0f / (e + 1.0f);
}

__device__ __forceinline__ short8 loadWfrag(const float* __restrict__ p) {
  float4 a = ((const float4*)p)[0];
  float4 b = ((const float4*)p)[1];
  short8 r;
  r[0] = (short)f2bf(a.x); r[1] = (short)f2bf(a.y);
  r[2] = (short)f2bf(a.z); r[3] = (short)f2bf(a.w);
  r[4] = (short)f2bf(b.x); r[5] = (short)f2bf(b.y);
  r[6] = (short)f2bf(b.z); r[7] = (short)f2bf(b.w);
  return r;
}

// 16B store, LLC-visible (write-through past L1+L2)
__device__ __forceinline__ void st16(void* p, i32x4 v) {
  asm volatile("global_store_dwordx4 %0, %1, off sc0 sc1" :: "v"(p), "v"(v) : "memory");
}

// h chunk loads: 16 x dwordx4 at 64B stride, LLC scope (bypass stale L1/L2)
#define LDH1(i, OFF)                                                          \
  asm volatile("global_load_dwordx4 %0, %1, off offset:" OFF " sc0 sc1"       \
               : "=v"(hf[i]) : "v"(hsrc) : "memory")
#define LDH_ALL()                                                             \
  LDH1(0, "0"); LDH1(1, "64"); LDH1(2, "128"); LDH1(3, "192");                \
  LDH1(4, "256"); LDH1(5, "320"); LDH1(6, "384"); LDH1(7, "448");             \
  LDH1(8, "512"); LDH1(9, "576"); LDH1(10, "640"); LDH1(11, "704");           \
  LDH1(12, "768"); LDH1(13, "832"); LDH1(14, "896"); LDH1(15, "960")

#define LDX1(i, OFF)                                                          \
  asm volatile("global_load_dwordx4 %0, %1, off offset:" OFF                  \
               : "=v"(xf[i]) : "v"(xsrc) : "memory")
#define LDX_ALL()                                                             \
  LDX1(0, "0"); LDX1(1, "64"); LDX1(2, "128"); LDX1(3, "192");                \
  LDX1(4, "256"); LDX1(5, "320"); LDX1(6, "384"); LDX1(7, "448");             \
  LDX1(8, "512"); LDX1(9, "576"); LDX1(10, "640"); LDX1(11, "704");           \
  LDX1(12, "768"); LDX1(13, "832"); LDX1(14, "896"); LDX1(15, "960")

// ---- prep: convert X (T,B,I) fp32 -> bf16 in ws. 16384x256 threads.
__global__ void prep_x(const float4* __restrict__ x, ushort4* __restrict__ xb) {
  int i = blockIdx.x * 256 + threadIdx.x;
  float4 v = x[i];
  ushort4 o;
  o.x = f2bf(v.x); o.y = f2bf(v.y); o.z = f2bf(v.z); o.w = f2bf(v.w);
  xb[i] = o;
}

// ---- prep: 8-buffer rotation per dir. buf0 = f2bf(h0); bufs 1..7 = sentinel.
// hbufs linear: dir (2) x buf (8) x 32768 ushorts. 2048x256 threads.
__global__ void prep_init(const float* __restrict__ h0f, const float* __restrict__ h0b,
                          unsigned short* __restrict__ hbufs) {
  int i = blockIdx.x * 256 + threadIdx.x;          // < 524288
  int dir = i >> 18;
  int rem = i & 262143;
  int buf = rem >> 15;
  int idx = rem & 32767;
  const float* src = dir ? h0b : h0f;
  hbufs[i] = (buf == 0) ? f2bf(src[idx]) : (unsigned short)0x7FC0;
}

// ---- persistent bidirectional LSTM. grid=128 (64 WGs/dir), block=256.
// SELF-SIGNALING DATAFLOW (no flags, no barriers, no LDS):
//   h^(s) lives in buf[s&7] (per dir). Producers write each (row, 8-unit)
//   chunk as ONE dwordx4; the bf16 NaN pattern 0x7FC0 is the "empty"
//   sentinel (unreachable: h = tanh outputs, |h|<=1). Consumers poll the
//   data itself: re-load their 16 chunks until all 4 dwords of each are
//   non-sentinel, then consume those same registers.
// Reuse safety (wave-local ordering only): each chunk is cleared to
//   sentinel by ITS OWN FUTURE WRITER. At step s a wave clears its chunks
//   of buf[(s+2)&7] (which holds h^(s-6): all readers retired, since
//   passing poll s-1 implies every wave is >= step s-2, i.e. reads <= s-3
//   retired). The clear drains at this step's poll vmcnt(0) -- BEFORE the
//   wave's h^(s+1) store issues -- so any consumer that has seen this
//   wave's h^(s+1) chunk is guaranteed to see the clear too: a non-sentinel
//   dword is always current-generation data. Writer of a chunk at step s+1
//   == clearer at step s (same wave), so no cross-wave clear race.
// Deadlock-free: only blocking point is the data poll; every producer
//   reaches its store unconditionally; 128 blocks @ (256,1) co-resident.
__global__ __launch_bounds__(256, 1) void lstm_coop(
    const unsigned short* __restrict__ xbf,
    unsigned short* __restrict__ hbufs,
    const float* __restrict__ Wih_f, const float* __restrict__ Whh_f,
    const float* __restrict__ bih_f, const float* __restrict__ bhh_f,
    const float* __restrict__ c0_f,
    const float* __restrict__ Wih_b, const float* __restrict__ Whh_b,
    const float* __restrict__ bih_b, const float* __restrict__ bhh_b,
    const float* __restrict__ c0_b,
    float* __restrict__ out) {
  const int tid = threadIdx.x;
  const int wave = tid >> 6;
  const int lane = tid & 63;
  const int quad = lane >> 4;
  const int lm = lane & 15;

  const int wg = blockIdx.x;
  const int dir = wg >> 6;       // 0 = forward, 1 = backward
  const int jw = wg & 63;        // hidden-slice index
  const int hb = jw * 8;         // first hidden unit owned

  const float* Wih = dir ? Wih_b : Wih_f;
  const float* Whh = dir ? Whh_b : Whh_f;
  const float* bih = dir ? bih_b : bih_f;
  const float* bhh = dir ? bhh_b : bhh_f;
  const float* c0  = dir ? c0_b  : c0_f;

  // ---- weight fragments: 32 gate rows x K=512, both matrices, in registers ----
  short8 wx[2][16], wh[2][16];
#pragma unroll
  for (int nt = 0; nt < 2; ++nt) {
    int nl = nt * 16 + lm;
    int row = (nl >> 3) * 512 + hb + (nl & 7);
#pragma unroll
    for (int kk = 0; kk < 16; ++kk) {
      int k = kk * 32 + quad * 8;
      wx[nt][kk] = loadWfrag(Wih + (size_t)row * 512 + k);
      wh[nt][kk] = loadWfrag(Whh + (size_t)row * 512 + k);
    }
  }

  // epilogue ownership: lane (quad,lm): unit u=lm&7 (lm>=8 duplicates),
  // batch rows b0..b0+3 of this wave's 16.
  const int u = lm & 7;
  float bsum[4];
#pragma unroll
  for (int g = 0; g < 4; ++g)
    bsum[g] = bih[g * 512 + hb + u] + bhh[g * 512 + hb + u];

  const int b0 = wave * 16 + quad * 4;
  float creg[4], hlast[4];
#pragma unroll
  for (int r = 0; r < 4; ++r) {
    creg[r] = c0[(size_t)(b0 + r) * 512 + hb + u];
    hlast[r] = 0.f;
  }

  // ---- pointers ----
  char* hdir = (char*)hbufs + (size_t)dir * 8 * 65536;     // 8 rotating 64KB buffers
  const int arow = wave * 16 + lm;                          // A-fragment batch row
  const char* hload_lane = hdir + (size_t)arow * 1024 + quad * 16;
  // producer store row: r0 covered by lanes lm={0,2,4,6} per quad
  const int r0 = (lm & 2) | ((lm & 4) >> 2);
  char* hstore_lane = hdir + (size_t)(wave * 16 + quad * 4 + r0) * 1024 + jw * 16;
  const bool wr = (lm < 8) && ((lm & 1) == 0);
  const char* xb_lane = (const char*)xbf + (size_t)arow * 1024 + quad * 16;

  const i32x4 sent4 = {SENT32, SENT32, SENT32, SENT32};

  // ---- initial x prefetch (drained so loop-top vmcnt(3) counts only A/H) ----
  short8 xf[16];
  {
    const char* xsrc = xb_lane + (size_t)(dir ? 511 : 0) * 65536;
    LDX_ALL();
  }
  asm volatile("s_waitcnt vmcnt(0)" ::: "memory");

  for (int s = 0; s < 512; ++s) {
    const int t = dir ? (511 - s) : s;

    // A: clear my future chunks in buf[(s+2)&7] (holds retired h^(s-6))
    if (wr) st16(hstore_lane + (size_t)((s + 2) & 7) * 65536, sent4);

    // wait for xf (allow 3 youngest: 2 out stores + clear), then x MFMAs
    asm volatile("s_waitcnt vmcnt(3)" ::: "memory");
    __builtin_amdgcn_sched_barrier(0);
    f32x4 acc0 = {0.f, 0.f, 0.f, 0.f};
    f32x4 acc1 = {0.f, 0.f, 0.f, 0.f};
#pragma unroll
    for (int kk = 0; kk < 16; ++kk) {
      acc0 = MFMA(xf[kk], wx[0][kk], acc0);
      acc1 = MFMA(xf[kk], wx[1][kk], acc1);
    }

    // C: self-signaling poll -- reload h chunks until all non-sentinel.
    // (also drains the clear A before this step's h-store F)
    short8 hf[16];
    {
      const char* hsrc = hload_lane + (size_t)(s & 7) * 65536;
      int ok;
      do {
        LDH_ALL();
        asm volatile("s_waitcnt vmcnt(0)" ::: "memory");
        __builtin_amdgcn_sched_barrier(0);
        ok = 1;
#pragma unroll
        for (int i = 0; i < 16; ++i) {
          i32x4 w = __builtin_bit_cast(i32x4, hf[i]);
          ok &= (w[0] != SENT32) & (w[1] != SENT32) &
                (w[2] != SENT32) & (w[3] != SENT32);
        }
      } while (!__all(ok));
    }

    // D: h MFMAs (fragments already in registers from the poll)
#pragma unroll
    for (int kk = 0; kk < 16; ++kk) {
      acc0 = MFMA(hf[kk], wh[0][kk], acc0);
      acc1 = MFMA(hf[kk], wh[1][kk], acc1);
    }

    // E: gate exchange within lane pair (lm ^ 8); D col=lane&15, row=quad*4+r
    float hv[4];
#pragma unroll
    for (int r = 0; r < 4; ++r) {
      float p0 = __shfl_xor(acc0[r], 8, 64);
      float p1 = __shfl_xor(acc1[r], 8, 64);
      float gi  = (lm < 8 ? acc0[r] : p0) + bsum[0];
      float gfr = (lm < 8 ? p0 : acc0[r]) + bsum[1];
      float gg  = (lm < 8 ? acc1[r] : p1) + bsum[2];
      float go  = (lm < 8 ? p1 : acc1[r]) + bsum[3];
      float cn = sigm(gfr) * creg[r] + sigm(gi) * tanh_fast(gg);
      creg[r] = cn;
      hv[r] = sigm(go) * tanh_fast(cn);
      hlast[r] = hv[r];
    }
    // float unit-pair partners (also used for fp32 out stores)
    float q0 = __shfl_xor(hv[0], 1, 64), q1 = __shfl_xor(hv[1], 1, 64);
    float q2 = __shfl_xor(hv[2], 1, 64), q3 = __shfl_xor(hv[3], 1, 64);

    // pack tree: gather one full (row, 8-unit) 16B chunk per even lane.
    // V[r] = canonical unit-pair dword (even unit in low half) -> identical
    // across lane pairs; xor2 then xor4 grow units while splitting rows.
    {
      const int ue = ((lm & 1) == 0);
      int V0 = ue ? ((int)f2bf(hv[0]) | ((int)f2bf(q0) << 16))
                  : ((int)f2bf(q0) | ((int)f2bf(hv[0]) << 16));
      int V1 = ue ? ((int)f2bf(hv[1]) | ((int)f2bf(q1) << 16))
                  : ((int)f2bf(q1) | ((int)f2bf(hv[1]) << 16));
      int V2 = ue ? ((int)f2bf(hv[2]) | ((int)f2bf(q2) << 16))
                  : ((int)f2bf(q2) | ((int)f2bf(hv[2]) << 16));
      int V3 = ue ? ((int)f2bf(hv[3]) | ((int)f2bf(q3) << 16))
                  : ((int)f2bf(q3) | ((int)f2bf(hv[3]) << 16));
      int P0 = __shfl_xor(V0, 2, 64), P1 = __shfl_xor(V1, 2, 64);
      int P2 = __shfl_xor(V2, 2, 64), P3 = __shfl_xor(V3, 2, 64);
      // rows split by lm&2: low keeps rows {0,1}, high rows {2,3}; canonical
      // unit-pair order (own/partner arranged low-pair-first)
      int X0 = ((lm & 2) == 0) ? V0 : P2;
      int X1 = ((lm & 2) == 0) ? P0 : V2;
      int X2 = ((lm & 2) == 0) ? V1 : P3;
      int X3 = ((lm & 2) == 0) ? P1 : V3;
      int Y0 = __shfl_xor(X0, 4, 64), Y1 = __shfl_xor(X1, 4, 64);
      int Y2 = __shfl_xor(X2, 4, 64), Y3 = __shfl_xor(X3, 4, 64);
      i32x4 Z;
      if ((lm & 4) == 0) { Z[0] = X0; Z[1] = X1; Z[2] = Y0; Z[3] = Y1; }
      else               { Z[0] = Y2; Z[1] = Y3; Z[2] = X2; Z[3] = X3; }
      // F: h^(s+1) chunk store -- data IS the signal
      if (wr) st16(hstore_lane + (size_t)((s + 1) & 7) * 65536, Z);
    }

    // G: x prefetch for next step (16 loads; in flight across everything)
    {
      int sn = s + 1 < 512 ? s + 1 : 511;
      int tn = dir ? (511 - sn) : sn;
      const char* xsrc = xb_lane + (size_t)tn * 65536;
      LDX_ALL();
    }

    // H: out stores (plain cached fp32; off the critical path)
    if (lm < 8) {
      const int sel = lm & 1;
      float2 vA = sel ? make_float2(q2, hv[2]) : make_float2(hv[0], q0);
      float2 vB = sel ? make_float2(q3, hv[3]) : make_float2(hv[1], q1);
      float* ob = out + (size_t)t * 65536 + dir * 512 + hb + (lm & ~1);
      *(float2*)(ob + (size_t)(b0 + 2 * sel) * 1024) = vA;
      *(float2*)(ob + (size_t)(b0 + 2 * sel + 1) * 1024) = vB;
    }
  }

  // ---- final hT, cT ----
  if (lm < 8) {
    float* obase = out + 33554432 + dir * 65536;
#pragma unroll
    for (int r = 0; r < 4; ++r) {
      obase[(size_t)(b0 + r) * 512 + hb + u] = hlast[r];
      obase[32768 + (size_t)(b0 + r) * 512 + hb + u] = creg[r];
    }
  }
}

extern "C" void kernel_launch(void* const* d_in, const int* in_sizes, int n_in,
                              void* d_out, int out_size, void* d_ws, size_t ws_size,
                              hipStream_t stream) {
  (void)in_sizes; (void)n_in; (void)out_size; (void)ws_size;

  const float* X     = (const float*)d_in[0];
  const float* h0_f  = (const float*)d_in[1];
  const float* c0_f  = (const float*)d_in[2];
  const float* h0_b  = (const float*)d_in[3];
  const float* c0_b  = (const float*)d_in[4];
  const float* Wih_f = (const float*)d_in[5];
  const float* Whh_f = (const float*)d_in[6];
  const float* bih_f = (const float*)d_in[7];
  const float* bhh_f = (const float*)d_in[8];
  const float* Wih_b = (const float*)d_in[9];
  const float* Whh_b = (const float*)d_in[10];
  const float* bih_b = (const float*)d_in[11];
  const float* bhh_b = (const float*)d_in[12];
  float* out = (float*)d_out;

  unsigned short* xbf   = (unsigned short*)d_ws;                      // 33,554,432 B
  unsigned short* hbufs = (unsigned short*)((char*)d_ws + 33554432);  //  1,048,576 B (2 dirs x 8 x 64KB)

  prep_x<<<16384, 256, 0, stream>>>((const float4*)X, (ushort4*)xbf);
  prep_init<<<2048, 256, 0, stream>>>(h0_f, h0_b, hbufs);

  lstm_coop<<<dim3(128), dim3(256), 0, stream>>>(
      xbf, hbufs,
      Wih_f, Whh_f, bih_f, bhh_f, c0_f,
      Wih_b, Whh_b, bih_b, bhh_b, c0_b,
      out);
}

// Round 6
// 3157.080 us; speedup vs baseline: 1.5844x; 1.1467x over previous
//
#include <hip/hip_runtime.h>
#include <cstdint>
#include <cstddef>

#define T_ 512
#define B_ 64
#define I_ 512
#define H_ 512
#define SENT32 0x7FC07FC0

typedef __attribute__((ext_vector_type(8))) short short8;
typedef __attribute__((ext_vector_type(4))) float f32x4;
typedef __attribute__((ext_vector_type(4))) int i32x4;

#define MFMA(a, b, c) __builtin_amdgcn_mfma_f32_16x16x32_bf16((a), (b), (c), 0, 0, 0)

__device__ __forceinline__ unsigned short f2bf(float f) {
  union { float f; unsigned u; } v; v.f = f;
  unsigned r = v.u + 0x7fffu + ((v.u >> 16) & 1u);
  return (unsigned short)(r >> 16);
}

__device__ __forceinline__ float sigm(float x) { return 1.0f / (1.0f + __expf(-x)); }
__device__ __forceinline__ float tanh_fast(float x) {
  float e = __expf(2.0f * x);
  return 1.0f - 2.0f / (e + 1.0f);
}

__device__ __forceinline__ short8 loadWfrag(const float* __restrict__ p) {
  float4 a = ((const float4*)p)[0];
  float4 b = ((const float4*)p)[1];
  short8 r;
  r[0] = (short)f2bf(a.x); r[1] = (short)f2bf(a.y);
  r[2] = (short)f2bf(a.z); r[3] = (short)f2bf(a.w);
  r[4] = (short)f2bf(b.x); r[5] = (short)f2bf(b.y);
  r[6] = (short)f2bf(b.z); r[7] = (short)f2bf(b.w);
  return r;
}

// 16B store, LLC-visible (write-through past L1+L2)
__device__ __forceinline__ void st16(void* p, i32x4 v) {
  asm volatile("global_store_dwordx4 %0, %1, off sc0 sc1" :: "v"(p), "v"(v) : "memory");
}

// h chunk loads: dwordx4 at 64B stride, LLC scope (bypass stale L1/L2)
#define LDH1(i, OFF)                                                          \
  asm volatile("global_load_dwordx4 %0, %1, off offset:" OFF " sc0 sc1"       \
               : "=v"(hf[i]) : "v"(hsrc) : "memory")
#define LDH_ALL()                                                             \
  LDH1(0, "0"); LDH1(1, "64"); LDH1(2, "128"); LDH1(3, "192");                \
  LDH1(4, "256"); LDH1(5, "320"); LDH1(6, "384"); LDH1(7, "448");             \
  LDH1(8, "512"); LDH1(9, "576"); LDH1(10, "640"); LDH1(11, "704");           \
  LDH1(12, "768"); LDH1(13, "832"); LDH1(14, "896"); LDH1(15, "960")
// conditional variants (issued only while chunk kk is still sentinel)
#define LDH_IF(i, OFF) if (!((done >> i) & 1u)) { LDH1(i, OFF); }
#define LDH_MISSING()                                                         \
  LDH_IF(0, "0") LDH_IF(1, "64") LDH_IF(2, "128") LDH_IF(3, "192")            \
  LDH_IF(4, "256") LDH_IF(5, "320") LDH_IF(6, "384") LDH_IF(7, "448")         \
  LDH_IF(8, "512") LDH_IF(9, "576") LDH_IF(10, "640") LDH_IF(11, "704")       \
  LDH_IF(12, "768") LDH_IF(13, "832") LDH_IF(14, "896") LDH_IF(15, "960")

#define LDX1(i, OFF)                                                          \
  asm volatile("global_load_dwordx4 %0, %1, off offset:" OFF                  \
               : "=v"(xf[i]) : "v"(xsrc) : "memory")
#define LDX_ALL()                                                             \
  LDX1(0, "0"); LDX1(1, "64"); LDX1(2, "128"); LDX1(3, "192");                \
  LDX1(4, "256"); LDX1(5, "320"); LDX1(6, "384"); LDX1(7, "448");             \
  LDX1(8, "512"); LDX1(9, "576"); LDX1(10, "640"); LDX1(11, "704");           \
  LDX1(12, "768"); LDX1(13, "832"); LDX1(14, "896"); LDX1(15, "960")

// ---- prep: convert X (T,B,I) fp32 -> bf16 in ws. 16384x256 threads.
__global__ void prep_x(const float4* __restrict__ x, ushort4* __restrict__ xb) {
  int i = blockIdx.x * 256 + threadIdx.x;
  float4 v = x[i];
  ushort4 o;
  o.x = f2bf(v.x); o.y = f2bf(v.y); o.z = f2bf(v.z); o.w = f2bf(v.w);
  xb[i] = o;
}

// ---- prep: 8-buffer rotation per dir. buf0 = f2bf(h0); bufs 1..7 = sentinel.
__global__ void prep_init(const float* __restrict__ h0f, const float* __restrict__ h0b,
                          unsigned short* __restrict__ hbufs) {
  int i = blockIdx.x * 256 + threadIdx.x;          // < 524288
  int dir = i >> 18;
  int rem = i & 262143;
  int buf = rem >> 15;
  int idx = rem & 32767;
  const float* src = dir ? h0b : h0f;
  hbufs[i] = (buf == 0) ? f2bf(src[idx]) : (unsigned short)0x7FC0;
}

// ---- persistent bidirectional LSTM. grid=128 (64 WGs/dir), block=256.
// SELF-SIGNALING + INCREMENTAL CONSUMPTION (no flags, barriers, LDS):
//   h^(s) lives in buf[s&7] (per dir), chunk = (batch row, 8 units) as ONE
//   dwordx4; bf16 NaN 0x7FC0 = "empty" (unreachable, |h|<=1). Consumers
//   poll the data; chunk column kk (64B across the wave) is an MFMA's
//   A-operand, wave-uniformly checkable with __all. Each round: vmcnt(0)
//   -> find newly-complete kk -> re-issue loads ONLY for missing kk (fly
//   during MFMAs) -> run the 2 MFMAs of each new kk -> exit at done=0xFFFF.
//   Poll traffic decays to the straggler chunks; MFMA work overlaps the
//   wait; tail after last arrival = 2 MFMAs.
// Reuse safety (wave-local ordering only): chunk cleared to sentinel by ITS
//   OWN FUTURE WRITER. At step s a wave clears its chunks of buf[(s+2)&7]
//   (holds h^(s-6): retired, since passing poll s-1 implies all waves >=
//   s-2, reads <= s-3 done). Clear drains at this step's first poll
//   vmcnt(0) -- before h^(s+1) store F issues -- so a non-sentinel dword is
//   always current-generation. Writer at s+1 == clearer at s (same wave).
// h-MFMA accumulation order = chunk arrival order (fp32 reorder ~1e-6).
// Deadlock-free: only blocking point is the data poll; every producer
//   reaches its store unconditionally; 128 blocks @ (256,1) co-resident.
__global__ __launch_bounds__(256, 1) void lstm_coop(
    const unsigned short* __restrict__ xbf,
    unsigned short* __restrict__ hbufs,
    const float* __restrict__ Wih_f, const float* __restrict__ Whh_f,
    const float* __restrict__ bih_f, const float* __restrict__ bhh_f,
    const float* __restrict__ c0_f,
    const float* __restrict__ Wih_b, const float* __restrict__ Whh_b,
    const float* __restrict__ bih_b, const float* __restrict__ bhh_b,
    const float* __restrict__ c0_b,
    float* __restrict__ out) {
  const int tid = threadIdx.x;
  const int wave = tid >> 6;
  const int lane = tid & 63;
  const int quad = lane >> 4;
  const int lm = lane & 15;

  const int wg = blockIdx.x;
  const int dir = wg >> 6;       // 0 = forward, 1 = backward
  const int jw = wg & 63;        // hidden-slice index
  const int hb = jw * 8;         // first hidden unit owned

  const float* Wih = dir ? Wih_b : Wih_f;
  const float* Whh = dir ? Whh_b : Whh_f;
  const float* bih = dir ? bih_b : bih_f;
  const float* bhh = dir ? bhh_b : bhh_f;
  const float* c0  = dir ? c0_b  : c0_f;

  // ---- weight fragments: 32 gate rows x K=512, both matrices, in registers ----
  short8 wx[2][16], wh[2][16];
#pragma unroll
  for (int nt = 0; nt < 2; ++nt) {
    int nl = nt * 16 + lm;
    int row = (nl >> 3) * 512 + hb + (nl & 7);
#pragma unroll
    for (int kk = 0; kk < 16; ++kk) {
      int k = kk * 32 + quad * 8;
      wx[nt][kk] = loadWfrag(Wih + (size_t)row * 512 + k);
      wh[nt][kk] = loadWfrag(Whh + (size_t)row * 512 + k);
    }
  }

  // epilogue ownership: lane (quad,lm): unit u=lm&7 (lm>=8 duplicates),
  // batch rows b0..b0+3 of this wave's 16.
  const int u = lm & 7;
  float bsum[4];
#pragma unroll
  for (int g = 0; g < 4; ++g)
    bsum[g] = bih[g * 512 + hb + u] + bhh[g * 512 + hb + u];

  const int b0 = wave * 16 + quad * 4;
  float creg[4], hlast[4];
#pragma unroll
  for (int r = 0; r < 4; ++r) {
    creg[r] = c0[(size_t)(b0 + r) * 512 + hb + u];
    hlast[r] = 0.f;
  }

  // ---- pointers ----
  char* hdir = (char*)hbufs + (size_t)dir * 8 * 65536;     // 8 rotating 64KB buffers
  const int arow = wave * 16 + lm;                          // A-fragment batch row
  const char* hload_lane = hdir + (size_t)arow * 1024 + quad * 16;
  // producer store row: r0 covered by lanes lm={0,2,4,6} per quad
  const int r0 = (lm & 2) | ((lm & 4) >> 2);
  char* hstore_lane = hdir + (size_t)(wave * 16 + quad * 4 + r0) * 1024 + jw * 16;
  const bool wr = (lm < 8) && ((lm & 1) == 0);
  const char* xb_lane = (const char*)xbf + (size_t)arow * 1024 + quad * 16;

  const i32x4 sent4 = {SENT32, SENT32, SENT32, SENT32};

  // ---- initial x prefetch (drained so loop-top vmcnt(3) counts only A/H) ----
  short8 xf[16];
  {
    const char* xsrc = xb_lane + (size_t)(dir ? 511 : 0) * 65536;
    LDX_ALL();
  }
  asm volatile("s_waitcnt vmcnt(0)" ::: "memory");

  for (int s = 0; s < 512; ++s) {
    const int t = dir ? (511 - s) : s;

    // A: clear my future chunks in buf[(s+2)&7] (holds retired h^(s-6))
    if (wr) st16(hstore_lane + (size_t)((s + 2) & 7) * 65536, sent4);

    // wait for xf (allow 3 youngest: 2 out stores + clear)
    asm volatile("s_waitcnt vmcnt(3)" ::: "memory");
    __builtin_amdgcn_sched_barrier(0);

    // B: issue the full h^(s) chunk-load round FIRST (flight overlaps x MFMAs)
    const char* hsrc = hload_lane + (size_t)(s & 7) * 65536;
    short8 hf[16];
    LDH_ALL();
    __builtin_amdgcn_sched_barrier(0);

    // x MFMAs (no h dependency; run while the h round is in flight)
    f32x4 acc0 = {0.f, 0.f, 0.f, 0.f};
    f32x4 acc1 = {0.f, 0.f, 0.f, 0.f};
#pragma unroll
    for (int kk = 0; kk < 16; ++kk) {
      acc0 = MFMA(xf[kk], wx[0][kk], acc0);
      acc1 = MFMA(xf[kk], wx[1][kk], acc1);
    }

    // C: incremental poll-and-consume. Chunk column kk valid (wave-uniform)
    // -> immediately MFMA it; reload only missing columns each round.
    {
      unsigned done = 0;
      while (true) {
        asm volatile("s_waitcnt vmcnt(0)" ::: "memory");  // also drains clear A
        __builtin_amdgcn_sched_barrier(0);
        unsigned newly = 0;
#pragma unroll
        for (int kk = 0; kk < 16; ++kk) {
          if (!((done >> kk) & 1u)) {
            i32x4 w = __builtin_bit_cast(i32x4, hf[kk]);
            int ok = (w[0] != SENT32) & (w[1] != SENT32) &
                     (w[2] != SENT32) & (w[3] != SENT32);
            if (__all(ok)) newly |= 1u << kk;
          }
        }
        done |= newly;
        // re-issue loads for still-missing chunks NOW (fly during MFMAs)
        if (done != 0xFFFFu) { LDH_MISSING(); }
        // consume the newly-arrived chunks
#pragma unroll
        for (int kk = 0; kk < 16; ++kk) {
          if ((newly >> kk) & 1u) {
            acc0 = MFMA(hf[kk], wh[0][kk], acc0);
            acc1 = MFMA(hf[kk], wh[1][kk], acc1);
          }
        }
        if (done == 0xFFFFu) break;
      }
    }

    // E: gate exchange within lane pair (lm ^ 8); D col=lane&15, row=quad*4+r
    float hv[4];
#pragma unroll
    for (int r = 0; r < 4; ++r) {
      float p0 = __shfl_xor(acc0[r], 8, 64);
      float p1 = __shfl_xor(acc1[r], 8, 64);
      float gi  = (lm < 8 ? acc0[r] : p0) + bsum[0];
      float gfr = (lm < 8 ? p0 : acc0[r]) + bsum[1];
      float gg  = (lm < 8 ? acc1[r] : p1) + bsum[2];
      float go  = (lm < 8 ? p1 : acc1[r]) + bsum[3];
      float cn = sigm(gfr) * creg[r] + sigm(gi) * tanh_fast(gg);
      creg[r] = cn;
      hv[r] = sigm(go) * tanh_fast(cn);
      hlast[r] = hv[r];
    }
    // float unit-pair partners (also used for fp32 out stores)
    float q0 = __shfl_xor(hv[0], 1, 64), q1 = __shfl_xor(hv[1], 1, 64);
    float q2 = __shfl_xor(hv[2], 1, 64), q3 = __shfl_xor(hv[3], 1, 64);

    // pack tree: gather one full (row, 8-unit) 16B chunk per even lane.
    {
      const int ue = ((lm & 1) == 0);
      int V0 = ue ? ((int)f2bf(hv[0]) | ((int)f2bf(q0) << 16))
                  : ((int)f2bf(q0) | ((int)f2bf(hv[0]) << 16));
      int V1 = ue ? ((int)f2bf(hv[1]) | ((int)f2bf(q1) << 16))
                  : ((int)f2bf(q1) | ((int)f2bf(hv[1]) << 16));
      int V2 = ue ? ((int)f2bf(hv[2]) | ((int)f2bf(q2) << 16))
                  : ((int)f2bf(q2) | ((int)f2bf(hv[2]) << 16));
      int V3 = ue ? ((int)f2bf(hv[3]) | ((int)f2bf(q3) << 16))
                  : ((int)f2bf(q3) | ((int)f2bf(hv[3]) << 16));
      int P0 = __shfl_xor(V0, 2, 64), P1 = __shfl_xor(V1, 2, 64);
      int P2 = __shfl_xor(V2, 2, 64), P3 = __shfl_xor(V3, 2, 64);
      int X0 = ((lm & 2) == 0) ? V0 : P2;
      int X1 = ((lm & 2) == 0) ? P0 : V2;
      int X2 = ((lm & 2) == 0) ? V1 : P3;
      int X3 = ((lm & 2) == 0) ? P1 : V3;
      int Y0 = __shfl_xor(X0, 4, 64), Y1 = __shfl_xor(X1, 4, 64);
      int Y2 = __shfl_xor(X2, 4, 64), Y3 = __shfl_xor(X3, 4, 64);
      i32x4 Z;
      if ((lm & 4) == 0) { Z[0] = X0; Z[1] = X1; Z[2] = Y0; Z[3] = Y1; }
      else               { Z[0] = Y2; Z[1] = Y3; Z[2] = X2; Z[3] = X3; }
      // F: h^(s+1) chunk store -- data IS the signal
      if (wr) st16(hstore_lane + (size_t)((s + 1) & 7) * 65536, Z);
    }

    // G: x prefetch for next step (16 loads; in flight across everything)
    {
      int sn = s + 1 < 512 ? s + 1 : 511;
      int tn = dir ? (511 - sn) : sn;
      const char* xsrc = xb_lane + (size_t)tn * 65536;
      LDX_ALL();
    }

    // H: out stores (plain cached fp32; off the critical path)
    if (lm < 8) {
      const int sel = lm & 1;
      float2 vA = sel ? make_float2(q2, hv[2]) : make_float2(hv[0], q0);
      float2 vB = sel ? make_float2(q3, hv[3]) : make_float2(hv[1], q1);
      float* ob = out + (size_t)t * 65536 + dir * 512 + hb + (lm & ~1);
      *(float2*)(ob + (size_t)(b0 + 2 * sel) * 1024) = vA;
      *(float2*)(ob + (size_t)(b0 + 2 * sel + 1) * 1024) = vB;
    }
  }

  // ---- final hT, cT ----
  if (lm < 8) {
    float* obase = out + 33554432 + dir * 65536;
#pragma unroll
    for (int r = 0; r < 4; ++r) {
      obase[(size_t)(b0 + r) * 512 + hb + u] = hlast[r];
      obase[32768 + (size_t)(b0 + r) * 512 + hb + u] = creg[r];
    }
  }
}

extern "C" void kernel_launch(void* const* d_in, const int* in_sizes, int n_in,
                              void* d_out, int out_size, void* d_ws, size_t ws_size,
                              hipStream_t stream) {
  (void)in_sizes; (void)n_in; (void)out_size; (void)ws_size;

  const float* X     = (const float*)d_in[0];
  const float* h0_f  = (const float*)d_in[1];
  const float* c0_f  = (const float*)d_in[2];
  const float* h0_b  = (const float*)d_in[3];
  const float* c0_b  = (const float*)d_in[4];
  const float* Wih_f = (const float*)d_in[5];
  const float* Whh_f = (const float*)d_in[6];
  const float* bih_f = (const float*)d_in[7];
  const float* bhh_f = (const float*)d_in[8];
  const float* Wih_b = (const float*)d_in[9];
  const float* Whh_b = (const float*)d_in[10];
  const float* bih_b = (const float*)d_in[11];
  const float* bhh_b = (const float*)d_in[12];
  float* out = (float*)d_out;

  unsigned short* xbf   = (unsigned short*)d_ws;                      // 33,554,432 B
  unsigned short* hbufs = (unsigned short*)((char*)d_ws + 33554432);  //  1,048,576 B (2 dirs x 8 x 64KB)

  prep_x<<<16384, 256, 0, stream>>>((const float4*)X, (ushort4*)xbf);
  prep_init<<<2048, 256, 0, stream>>>(h0_f, h0_b, hbufs);

  lstm_coop<<<dim3(128), dim3(256), 0, stream>>>(
      xbf, hbufs,
      Wih_f, Whh_f, bih_f, bhh_f, c0_f,
      Wih_b, Whh_b, bih_b, bhh_b, c0_b,
      out);
}